// Round 25
// baseline (151.139 us; speedup 1.0000x reference)
//
#include <hip/hip_runtime.h>
#include <hip/hip_bf16.h>
#include <stdint.h>

typedef __attribute__((ext_vector_type(8))) short bf16x8;
typedef __attribute__((ext_vector_type(4))) float f32x4;

#define T_TOKENS 8192
#define DIM 1024
#define NEXP 8
#define BUFSZ 24576  // A[128][64B] = 8192, B[256][64B]x2 = 16384

__device__ __forceinline__ unsigned short f2bf(float f) {
  unsigned u = __float_as_uint(f);
  u = (u + 0x7FFFu + ((u >> 16) & 1u)) >> 16;
  return (unsigned short)u;
}

// ---------------- router: fp32 logits, top-2; writes ONE unscaled bf16 copy of x ----------------
__global__ __launch_bounds__(256) void router_kernel(
    const float* __restrict__ x, const float* __restrict__ gw, const float* __restrict__ gb,
    float* __restrict__ logits_out, unsigned short* __restrict__ xw,
    int* __restrict__ tk_e, float* __restrict__ tk_w) {
  int wave = threadIdx.x >> 6, lane = threadIdx.x & 63;
  int t = blockIdx.x * 4 + wave;
  float acc[NEXP];
#pragma unroll
  for (int e = 0; e < NEXP; ++e) acc[e] = 0.f;
  const float4* xr = (const float4*)(x + (size_t)t * DIM);
  ushort4* xo = (ushort4*)(xw + (size_t)t * DIM);
#pragma unroll
  for (int it = 0; it < 4; ++it) {
    int d4 = it * 64 + lane;
    float4 xv = xr[d4];
    ushort4 xb;
    xb.x = f2bf(xv.x); xb.y = f2bf(xv.y); xb.z = f2bf(xv.z); xb.w = f2bf(xv.w);
    xo[d4] = xb;
#pragma unroll
    for (int e = 0; e < NEXP; ++e) {
      float4 gv = ((const float4*)(gw + e * DIM))[d4];
      acc[e] += xv.x * gv.x + xv.y * gv.y + xv.z * gv.z + xv.w * gv.w;
    }
  }
#pragma unroll
  for (int off = 32; off; off >>= 1)
#pragma unroll
    for (int e = 0; e < NEXP; ++e) acc[e] += __shfl_xor(acc[e], off);
  if (lane == 0) {
    float4 gb0 = ((const float4*)gb)[0];
    float4 gb1 = ((const float4*)gb)[1];
    acc[0] += gb0.x; acc[1] += gb0.y; acc[2] += gb0.z; acc[3] += gb0.w;
    acc[4] += gb1.x; acc[5] += gb1.y; acc[6] += gb1.z; acc[7] += gb1.w;
    float4* lp = (float4*)(logits_out + (size_t)t * NEXP);
    lp[0] = make_float4(acc[0], acc[1], acc[2], acc[3]);
    lp[1] = make_float4(acc[4], acc[5], acc[6], acc[7]);
    int e0 = 0; float l0 = acc[0];
#pragma unroll
    for (int e = 1; e < NEXP; ++e) if (acc[e] > l0) { l0 = acc[e]; e0 = e; }
    int e1 = -1; float l1 = -1e30f;
#pragma unroll
    for (int e = 0; e < NEXP; ++e) if (e != e0 && acc[e] > l1) { l1 = acc[e]; e1 = e; }
    float r = expf(l1 - l0);          // p1/p0
    float w0 = 1.f / (1.f + r);
    float w1 = r * w0;
    tk_e[t * 2] = e0; tk_e[t * 2 + 1] = e1;
    tk_w[t * 2] = w0; tk_w[t * 2 + 1] = w1;
  }
}

// ---------------- fused: block 0 = 8-bin counting sort (16384 pairs, parallel phase B);
// blocks 1..2048 = expert_w convert ----------------
__global__ __launch_bounds__(1024) void sortconv_kernel(
    const float* __restrict__ ew, unsigned short* __restrict__ w_bf,
    const int* __restrict__ tk_e, const float* __restrict__ tk_w,
    int* __restrict__ offsets_g, int* __restrict__ row_token,
    float* __restrict__ row_weight, int* __restrict__ tiles_g,
    int* __restrict__ n_tiles_g) {
  if (blockIdx.x > 0) {
    int i = (blockIdx.x - 1) * 1024 + threadIdx.x;  // 2M float4s
    float4 v = ((const float4*)ew)[i];
    ushort4 o;
    o.x = f2bf(v.x); o.y = f2bf(v.y); o.z = f2bf(v.z); o.w = f2bf(v.w);
    ((ushort4*)w_bf)[i] = o;
    return;
  }
  int tid = threadIdx.x;
  int lane = tid & 63, wv = tid >> 6;  // 16 waves, 16 pairs/thread
  __shared__ unsigned short excl16[NEXP][1024];  // 16 KB
  __shared__ int wavebase[16][NEXP];
  __shared__ int offs_l[NEXP + 1];

  int pe[16];
  float tw[16];
  const int base = tid * 16;
#pragma unroll
  for (int i = 0; i < 4; ++i) {
    int4 v = ((const int4*)(tk_e + base))[i];
    pe[i * 4 + 0] = v.x; pe[i * 4 + 1] = v.y; pe[i * 4 + 2] = v.z; pe[i * 4 + 3] = v.w;
    float4 w = ((const float4*)(tk_w + base))[i];
    tw[i * 4 + 0] = w.x; tw[i * 4 + 1] = w.y; tw[i * 4 + 2] = w.z; tw[i * 4 + 3] = w.w;
  }

#pragma unroll
  for (int p = 0; p < NEXP; ++p) {
    int cnt = 0;
#pragma unroll
    for (int i = 0; i < 16; ++i) cnt += (pe[i] == p);
    int incl = cnt;
#pragma unroll
    for (int off = 1; off < 64; off <<= 1) {
      int n = __shfl_up(incl, off);
      if (lane >= off) incl += n;
    }
    excl16[p][tid] = (unsigned short)(incl - cnt);
    if (lane == 63) wavebase[wv][p] = incl;
  }
  __syncthreads();

  // phase B: parallel over lanes 0..7 of wave 0
  if (wv == 0 && lane < NEXP) {
    const int p = lane;
    int tot = 0;
#pragma unroll
    for (int w = 0; w < 16; ++w) {
      int v = wavebase[w][p];
      wavebase[w][p] = tot;
      tot += v;
    }
    int incl = tot;
#pragma unroll
    for (int off = 1; off < 8; off <<= 1) {
      int n = __shfl_up(incl, off);
      if (lane >= off) incl += n;
    }
    int exc = incl - tot;
    offs_l[p] = exc;
    offsets_g[p] = exc;
    if (p == NEXP - 1) { offs_l[NEXP] = incl; offsets_g[NEXP] = incl; }
    // tile emission: mt m-tiles (BM=128) x 4 n-tiles (BN=256); scan counts for base
    int mt = (tot + 127) >> 7;
    int tcnt = 4 * mt;
    int tincl = tcnt;
#pragma unroll
    for (int off = 1; off < 8; off <<= 1) {
      int n = __shfl_up(tincl, off);
      if (lane >= off) tincl += n;
    }
    int tbase = tincl - tcnt;
    for (int m = 0; m < mt; ++m)
      for (int n = 0; n < 4; ++n) tiles_g[tbase + m * 4 + n] = p | (n << 4) | (m << 8);
    if (p == NEXP - 1) {
      n_tiles_g[0] = tincl;
      n_tiles_g[1] = (tincl + 7) >> 3;  // chunk size per XCD column
    }
  }
  __syncthreads();

#pragma unroll
  for (int i = 0; i < 16; ++i) {
    int p = pe[i];
    int rank = 0;
#pragma unroll
    for (int j = 0; j < 16; ++j)
      if (j < i) rank += (pe[j] == p);
    int pos = offs_l[p] + wavebase[wv][p] + (int)excl16[p][tid] + rank;
    row_token[pos] = (base + i) >> 1;
    row_weight[pos] = tw[i];
  }
}

// ---------------- grouped GEMM (R9-proven body): 128x256 tile, BK=32, triple-buffered LDS
// (3x24KB, 2 blocks/CU), counted vmcnt(3). Epilogue: fp32 atomicAdd of w*(acc+bias) into
// zeroed out — exactly 2 commutative adds per element -> deterministic; no tmp, no combine. ----------------
#define GLOAD16(g, l)                                                                   \
  __builtin_amdgcn_global_load_lds((const __attribute__((address_space(1))) unsigned int*)(g), \
                                   (__attribute__((address_space(3))) unsigned int*)(l), 16, 0, 0)

__global__ __launch_bounds__(512, 4) void gemm_kernel(
    const unsigned short* __restrict__ xw, const unsigned short* __restrict__ w_bf,
    const int* __restrict__ row_token, const float* __restrict__ row_weight,
    const int* __restrict__ offsets, const int* __restrict__ tiles,
    const int* __restrict__ n_tiles, const float* __restrict__ eb,
    float* __restrict__ out) {
  const int nb = n_tiles[0], cpx = n_tiles[1];
  const int wg = blockIdx.x;
  const int slot = wg >> 3;
  if (slot >= cpx) return;
  const int idx = (wg & 7) * cpx + slot;   // chunked: XCD column gets contiguous schedule run
  if (idx >= nb) return;
  const int s = tiles[idx];
  const int e = s & 7;
  const int n0 = ((s >> 4) & 3) << 8;
  const int m0 = (s >> 8) << 7;
  const int seg0 = offsets[e], segN = offsets[e + 1] - seg0;

  const int tid = threadIdx.x;
  const int lane = tid & 63, wave = tid >> 6;
  const int wr = wave >> 2, wc = wave & 3;  // 2M x 4N wave grid; wave output 64x64

  __shared__ __align__(16) char smem[3 * BUFSZ];

  const int arow = tid >> 2;
  const int swzc = ((tid & 3) ^ ((tid >> 3) & 3)) << 4;
  int gr0 = m0 + arow; if (gr0 > segN - 1) gr0 = segN - 1;
  const char* srcA = (const char*)xw + (size_t)row_token[seg0 + gr0] * 2048 + swzc;
  const char* srcB0 = (const char*)w_bf + (((size_t)e << 20) + (size_t)(n0 + arow) * 1024) * 2 + swzc;
  const char* srcB1 = srcB0 + 128 * 2048;  // +128 B-rows
  const int dA = tid * 16;
  const int dB0 = 8192 + tid * 16;
  const int dB1 = 16384 + tid * 16;

  const int rsw = (((lane >> 4) ^ (lane >> 1)) & 3) << 4;
  int aoff[4], boff[4];
#pragma unroll
  for (int m = 0; m < 4; ++m)
    aoff[m] = (wr * 64 + m * 16 + (lane & 15)) * 64 + rsw;
#pragma unroll
  for (int n = 0; n < 4; ++n)
    boff[n] = 8192 + (wc * 64 + n * 16 + (lane & 15)) * 64 + rsw;

  f32x4 acc[4][4];
#pragma unroll
  for (int m = 0; m < 4; ++m)
#pragma unroll
    for (int n = 0; n < 4; ++n) acc[m][n] = (f32x4){0.f, 0.f, 0.f, 0.f};

#define STAGE3(bufo, kb)                           \
  {                                                \
    GLOAD16(srcA + (kb), smem + (bufo) + dA);      \
    GLOAD16(srcB0 + (kb), smem + (bufo) + dB0);    \
    GLOAD16(srcB1 + (kb), smem + (bufo) + dB1);    \
  }

  // prologue: stage K-tiles 0,1 into buf0,buf1 (6 loads in flight)
  STAGE3(0, 0);
  STAGE3(BUFSZ, 64);

  int cb = 0;
  for (int kt = 0; kt < 32; ++kt) {
    if (kt < 31) {
      asm volatile("s_waitcnt vmcnt(3)" ::: "memory");  // retire tile kt's 3; keep kt+1's 3
    } else {
      asm volatile("s_waitcnt vmcnt(0)" ::: "memory");
    }
    __builtin_amdgcn_s_barrier();
    const int cur = cb * BUFSZ;
    bf16x8 a_[4], b_[4];
#pragma unroll
    for (int m = 0; m < 4; ++m) a_[m] = *(const bf16x8*)(smem + cur + aoff[m]);
#pragma unroll
    for (int n = 0; n < 4; ++n) b_[n] = *(const bf16x8*)(smem + cur + boff[n]);
    if (kt < 30) {
      int cbn = cb + 2; if (cbn >= 3) cbn -= 3;   // buffer for tile kt+2
      const int kbn = (kt + 2) * 64;              // BK=32 -> 64B per row per K-tile
      STAGE3(cbn * BUFSZ, kbn);
    }
    __builtin_amdgcn_s_setprio(1);
#pragma unroll
    for (int m = 0; m < 4; ++m)
#pragma unroll
      for (int n = 0; n < 4; ++n)
        acc[m][n] = __builtin_amdgcn_mfma_f32_16x16x32_bf16(a_[m], b_[n], acc[m][n], 0, 0, 0);
    __builtin_amdgcn_s_setprio(0);
    cb = (cb + 1 == 3) ? 0 : cb + 1;
  }

  // epilogue: atomic accumulate w*(acc + bias_e) into out (2 commutative adds/element total)
  const float* be_ = eb + e * 1024;
#pragma unroll
  for (int m = 0; m < 4; ++m) {
#pragma unroll
    for (int r = 0; r < 4; ++r) {
      int g = m0 + wr * 64 + m * 16 + ((lane >> 4) << 2) + r;
      if (g < segN) {
        int p = seg0 + g;
        float w = row_weight[p];
        float* op = out + (size_t)row_token[p] * 1024;
#pragma unroll
        for (int n = 0; n < 4; ++n) {
          int col = n0 + wc * 64 + n * 16 + (lane & 15);
          atomicAdd(&op[col], w * (acc[m][n][r] + be_[col]));
        }
      }
    }
  }
#undef STAGE3
}

extern "C" void kernel_launch(void* const* d_in, const int* in_sizes, int n_in,
                              void* d_out, int out_size, void* d_ws, size_t ws_size,
                              hipStream_t stream) {
  const float* x  = (const float*)d_in[0];
  const float* gw = (const float*)d_in[1];
  const float* gb = (const float*)d_in[2];
  const float* ew = (const float*)d_in[3];
  const float* eb = (const float*)d_in[4];
  float* out = (float*)d_out;
  float* logits = out + (size_t)T_TOKENS * 1024;

  char* ws = (char*)d_ws;
  unsigned short* xw   = (unsigned short*)(ws);                 // 16 MB (single unscaled copy)
  unsigned short* w_bf = (unsigned short*)(ws + 16777216);      // 16 MB
  int*    tk_e      = (int*)(ws + 33554432);
  float*  tk_w      = (float*)(ws + 33619968);
  int*    row_token = (int*)(ws + 33685504);
  float*  row_weight= (float*)(ws + 33751040);
  int*    offsets   = (int*)(ws + 33816576);   // 9 ints
  int*    n_tiles   = (int*)(ws + 33816704);   // [0]=nb, [1]=cpx
  int*    tiles     = (int*)(ws + 33816832);   // up to 544 ints

  hipMemsetAsync(out, 0, (size_t)T_TOKENS * 1024 * 4, stream);  // atomic base (logits untouched)
  router_kernel<<<2048, 256, 0, stream>>>(x, gw, gb, logits, xw, tk_e, tk_w);
  sortconv_kernel<<<2049, 1024, 0, stream>>>(ew, w_bf, tk_e, tk_w, offsets, row_token,
                                             row_weight, tiles, n_tiles);
  gemm_kernel<<<544, 512, 0, stream>>>(xw, w_bf, row_token, row_weight, offsets, tiles,
                                       n_tiles, eb, out);
}

// Round 26
// 99.600 us; speedup vs baseline: 1.5175x; 1.5175x over previous
//
#include <hip/hip_runtime.h>
#include <hip/hip_bf16.h>
#include <stdint.h>

typedef __attribute__((ext_vector_type(8))) short bf16x8;
typedef __attribute__((ext_vector_type(4))) float f32x4;

#define T_TOKENS 8192
#define DIM 1024
#define NEXP 8
#define NPAIR 28
#define BUFSZ 40960  // A[128][64B] = 8192, B[512][64B] = 32768

__device__ __forceinline__ unsigned short f2bf(float f) {
  unsigned u = __float_as_uint(f);
  u = (u + 0x7FFFu + ((u >> 16) & 1u)) >> 16;
  return (unsigned short)u;
}

// ---------------- router: fp32 logits, top-2; writes ONE unscaled bf16 copy of x ----------------
__global__ __launch_bounds__(256) void router_kernel(
    const float* __restrict__ x, const float* __restrict__ gw, const float* __restrict__ gb,
    float* __restrict__ logits_out, unsigned short* __restrict__ xw,
    int* __restrict__ tk_e, float* __restrict__ tk_w) {
  int wave = threadIdx.x >> 6, lane = threadIdx.x & 63;
  int t = blockIdx.x * 4 + wave;
  float acc[NEXP];
#pragma unroll
  for (int e = 0; e < NEXP; ++e) acc[e] = 0.f;
  const float4* xr = (const float4*)(x + (size_t)t * DIM);
  ushort4* xo = (ushort4*)(xw + (size_t)t * DIM);
#pragma unroll
  for (int it = 0; it < 4; ++it) {
    int d4 = it * 64 + lane;
    float4 xv = xr[d4];
    ushort4 xb;
    xb.x = f2bf(xv.x); xb.y = f2bf(xv.y); xb.z = f2bf(xv.z); xb.w = f2bf(xv.w);
    xo[d4] = xb;
#pragma unroll
    for (int e = 0; e < NEXP; ++e) {
      float4 gv = ((const float4*)(gw + e * DIM))[d4];
      acc[e] += xv.x * gv.x + xv.y * gv.y + xv.z * gv.z + xv.w * gv.w;
    }
  }
#pragma unroll
  for (int off = 32; off; off >>= 1)
#pragma unroll
    for (int e = 0; e < NEXP; ++e) acc[e] += __shfl_xor(acc[e], off);
  if (lane == 0) {
    float4 gb0 = ((const float4*)gb)[0];
    float4 gb1 = ((const float4*)gb)[1];
    acc[0] += gb0.x; acc[1] += gb0.y; acc[2] += gb0.z; acc[3] += gb0.w;
    acc[4] += gb1.x; acc[5] += gb1.y; acc[6] += gb1.z; acc[7] += gb1.w;
    float4* lp = (float4*)(logits_out + (size_t)t * NEXP);
    lp[0] = make_float4(acc[0], acc[1], acc[2], acc[3]);
    lp[1] = make_float4(acc[4], acc[5], acc[6], acc[7]);
    int e0 = 0; float l0 = acc[0];
#pragma unroll
    for (int e = 1; e < NEXP; ++e) if (acc[e] > l0) { l0 = acc[e]; e0 = e; }
    int e1 = -1; float l1 = -1e30f;
#pragma unroll
    for (int e = 0; e < NEXP; ++e) if (e != e0 && acc[e] > l1) { l1 = acc[e]; e1 = e; }
    float r = expf(l1 - l0);          // p1/p0
    float w0 = 1.f / (1.f + r);
    float w1 = r * w0;
    tk_e[t * 2] = e0; tk_e[t * 2 + 1] = e1;
    tk_w[t * 2] = w0; tk_w[t * 2 + 1] = w1;
  }
}

// ---------------- fused: block 0 = pair-sort (28 bins, LDS rank table, parallel phase B);
// blocks 1..2048 = expert_w convert ----------------
__global__ __launch_bounds__(1024) void sortconv_kernel(
    const float* __restrict__ ew, unsigned short* __restrict__ w_bf,
    const int* __restrict__ tk_e, const float* __restrict__ tk_w,
    int* __restrict__ offsets_g, int* __restrict__ row_tok,
    float2* __restrict__ row_wab, int* __restrict__ pairAB_g,
    int* __restrict__ tiles_g, int* __restrict__ n_tiles_g) {
  if (blockIdx.x > 0) {
    int i = (blockIdx.x - 1) * 1024 + threadIdx.x;  // 2M float4s
    float4 v = ((const float4*)ew)[i];
    ushort4 o;
    o.x = f2bf(v.x); o.y = f2bf(v.y); o.z = f2bf(v.z); o.w = f2bf(v.w);
    ((ushort4*)w_bf)[i] = o;
    return;
  }
  int tid = threadIdx.x;
  int lane = tid & 63, wv = tid >> 6;  // 16 waves, 8 tokens/thread
  __shared__ unsigned short excl16[NPAIR][1024];  // 56 KB
  __shared__ int wavebase[16][NPAIR];
  __shared__ int offs_l[NPAIR + 1];

  int pp[8];
  float wa_[8], wb_[8];
  const int base = tid * 8;
#pragma unroll
  for (int i = 0; i < 8; ++i) {
    int2 ev = ((const int2*)tk_e)[base + i];
    float2 wv2 = ((const float2*)tk_w)[base + i];
    int a, b;
    float wa, wb;
    if (ev.x < ev.y) { a = ev.x; b = ev.y; wa = wv2.x; wb = wv2.y; }
    else             { a = ev.y; b = ev.x; wa = wv2.y; wb = wv2.x; }
    pp[i] = a * (15 - a) / 2 + (b - a - 1);  // 0..27
    wa_[i] = wa; wb_[i] = wb;
  }

#pragma unroll
  for (int p = 0; p < NPAIR; ++p) {
    int cnt = 0;
#pragma unroll
    for (int i = 0; i < 8; ++i) cnt += (pp[i] == p);
    int incl = cnt;
#pragma unroll
    for (int off = 1; off < 64; off <<= 1) {
      int n = __shfl_up(incl, off);
      if (lane >= off) incl += n;
    }
    excl16[p][tid] = (unsigned short)(incl - cnt);
    if (lane == 63) wavebase[wv][p] = incl;
  }
  __syncthreads();

  // phase B: parallel over lanes 0..27 of wave 0
  if (wv == 0 && lane < NPAIR) {
    const int p = lane;
    int tot = 0;
#pragma unroll
    for (int w = 0; w < 16; ++w) {
      int v = wavebase[w][p];
      wavebase[w][p] = tot;
      tot += v;
    }
    int incl = tot;
#pragma unroll
    for (int off = 1; off < 32; off <<= 1) {
      int n = __shfl_up(incl, off);
      if (lane >= off) incl += n;
    }
    int exc = incl - tot;
    offs_l[p] = exc;
    offsets_g[p] = exc;
    if (p == NPAIR - 1) { offs_l[NPAIR] = incl; offsets_g[NPAIR] = incl; }
    int a = 0, b = 0, bse = 0;
#pragma unroll
    for (int aa = 0; aa < 7; ++aa) {
      int sz = 7 - aa;
      if (p >= bse && p < bse + sz) { a = aa; b = aa + 1 + (p - bse); }
      bse += sz;
    }
    pairAB_g[p] = a | (b << 4);
    int mt = (tot + 127) >> 7;
    int tcnt = 2 * mt;
    int tincl = tcnt;
#pragma unroll
    for (int off = 1; off < 32; off <<= 1) {
      int n = __shfl_up(tincl, off);
      if (lane >= off) tincl += n;
    }
    int tbase = tincl - tcnt;
    for (int n = 0; n < 2; ++n)
      for (int m = 0; m < mt; ++m) tiles_g[tbase + n * mt + m] = p | (n << 5) | (m << 6);
    if (p == NPAIR - 1) {
      n_tiles_g[0] = tincl;
      n_tiles_g[1] = (tincl + 7) >> 3;
    }
  }
  __syncthreads();

#pragma unroll
  for (int i = 0; i < 8; ++i) {
    int p = pp[i];
    int rank = 0;
#pragma unroll
    for (int j = 0; j < 8; ++j)
      if (j < i) rank += (pp[j] == p);
    int pos = offs_l[p] + wavebase[wv][p] + (int)excl16[p][tid] + rank;
    row_tok[pos] = base + i;
    row_wab[pos] = make_float2(wa_[i], wb_[i]);
  }
}

// ---------------- pair-fused grouped GEMM with ratio-deferred weighting (R22/R23-proven):
// acc = x@Wa (kt<32); seam acc *= wa/wbe; acc += x@Wb; out = wbe*acc + wa*ba + wbe*bb.
// 128x512 tile, BK=32, triple-buffered LDS (3x40KB, 1 block/CU), counted vmcnt(5). ----------------
#define GLOAD16(g, l)                                                                   \
  __builtin_amdgcn_global_load_lds((const __attribute__((address_space(1))) unsigned int*)(g), \
                                   (__attribute__((address_space(3))) unsigned int*)(l), 16, 0, 0)

__global__ __launch_bounds__(512, 2) void gemm_kernel(
    const unsigned short* __restrict__ xw, const unsigned short* __restrict__ w_bf,
    const int* __restrict__ row_tok, const float2* __restrict__ row_wab,
    const int* __restrict__ offsets, const int* __restrict__ pairAB,
    const int* __restrict__ tiles, const int* __restrict__ n_tiles,
    const float* __restrict__ eb, float* __restrict__ out) {
  const int nb = n_tiles[0], cpx = n_tiles[1];
  const int wg = blockIdx.x;
  const int slot = wg >> 3;
  if (slot >= cpx) return;
  const int idx = (wg & 7) * cpx + slot;
  if (idx >= nb) return;
  const int s = tiles[idx];
  const int pid = s & 31;
  const int n0 = ((s >> 5) & 1) << 9;
  const int m0 = (s >> 6) << 7;
  const int ab = pairAB[pid];
  const int ea = ab & 15, ebx = ab >> 4;
  const int seg0 = offsets[pid], segN = offsets[pid + 1] - seg0;

  const int tid = threadIdx.x;
  const int lane = tid & 63, wave = tid >> 6;
  const int wr = wave >> 2, wc = wave & 3;  // 2M x 4N; wave output 64x128

  __shared__ __align__(16) char smem[3 * BUFSZ];

  const int arow = tid >> 2;
  const int swzc = ((tid & 3) ^ ((tid >> 3) & 3)) << 4;
  const int dA = tid * 16;
  const int dB = 8192 + tid * 16;

  int gr0 = m0 + arow; if (gr0 > segN - 1) gr0 = segN - 1;
  const char* srcA = (const char*)xw + (size_t)row_tok[seg0 + gr0] * 2048 + swzc;
  const char* srcBa = (const char*)w_bf + (((size_t)ea << 20) + (size_t)(n0 + arow) * 1024) * 2 + swzc;
  const char* srcBb = (const char*)w_bf + (((size_t)ebx << 20) + (size_t)(n0 + arow) * 1024) * 2 + swzc;

  float rat[4][4], wav[4][4], wbe[4][4];
#pragma unroll
  for (int m = 0; m < 4; ++m) {
#pragma unroll
    for (int r = 0; r < 4; ++r) {
      int g = m0 + wr * 64 + m * 16 + ((lane >> 4) << 2) + r;
      if (g > segN - 1) g = segN - 1;
      float2 wab = row_wab[seg0 + g];
      float we = fmaxf(wab.y, 1e-20f);
      wav[m][r] = wab.x;
      wbe[m][r] = we;
      rat[m][r] = wab.x / we;
    }
  }

  const int rsw = (((lane >> 4) ^ (lane >> 1)) & 3) << 4;
  int aoff[4], boff[8];
#pragma unroll
  for (int m = 0; m < 4; ++m)
    aoff[m] = (wr * 64 + m * 16 + (lane & 15)) * 64 + rsw;
#pragma unroll
  for (int n = 0; n < 8; ++n)
    boff[n] = 8192 + (wc * 128 + n * 16 + (lane & 15)) * 64 + rsw;

  f32x4 acc[4][8];
#pragma unroll
  for (int m = 0; m < 4; ++m)
#pragma unroll
    for (int n = 0; n < 8; ++n) acc[m][n] = (f32x4){0.f, 0.f, 0.f, 0.f};

#define STAGE5(bufo, pa, pb)                                   \
  {                                                            \
    GLOAD16((pa), smem + (bufo) + dA);                         \
    GLOAD16((pb), smem + (bufo) + dB);                         \
    GLOAD16((pb) + 262144, smem + (bufo) + dB + 8192);         \
    GLOAD16((pb) + 524288, smem + (bufo) + dB + 16384);        \
    GLOAD16((pb) + 786432, smem + (bufo) + dB + 24576);        \
  }
#define STAGEJ(bufo, j)                                                  \
  {                                                                      \
    if ((j) < 32) { const int kb = (j) * 64;                             \
      STAGE5(bufo, srcA + kb, srcBa + kb); }                             \
    else { const int kb = ((j) - 32) * 64;                               \
      STAGE5(bufo, srcA + kb, srcBb + kb); }                             \
  }

  // prologue: stage K-tiles 0,1 into buf0,buf1 (10 loads in flight)
  STAGEJ(0, 0);
  STAGEJ(BUFSZ, 1);

  int cb = 0;
  for (int kt = 0; kt < 64; ++kt) {
    if (kt < 63) {
      asm volatile("s_waitcnt vmcnt(5)" ::: "memory");  // retire tile kt's 5; keep kt+1's 5
    } else {
      asm volatile("s_waitcnt vmcnt(0)" ::: "memory");
    }
    __builtin_amdgcn_s_barrier();
    const int cur = cb * BUFSZ;
    bf16x8 a_[4], b_[8];
#pragma unroll
    for (int m = 0; m < 4; ++m) a_[m] = *(const bf16x8*)(smem + cur + aoff[m]);
#pragma unroll
    for (int n = 0; n < 8; ++n) b_[n] = *(const bf16x8*)(smem + cur + boff[n]);
    if (kt < 62) {
      int cbn = cb + 2; if (cbn >= 3) cbn -= 3;
      STAGEJ(cbn * BUFSZ, kt + 2);
    }
    if (kt == 32) {
      // seam: acc holds x@Wa; scale by wa/wbe per row so the Wb half can share the accumulator
#pragma unroll
      for (int m = 0; m < 4; ++m)
#pragma unroll
        for (int n = 0; n < 8; ++n)
#pragma unroll
          for (int r = 0; r < 4; ++r) acc[m][n][r] *= rat[m][r];
    }
    __builtin_amdgcn_s_setprio(1);
#pragma unroll
    for (int m = 0; m < 4; ++m)
#pragma unroll
      for (int n = 0; n < 8; ++n)
        acc[m][n] = __builtin_amdgcn_mfma_f32_16x16x32_bf16(a_[m], b_[n], acc[m][n], 0, 0, 0);
    __builtin_amdgcn_s_setprio(0);
    cb = (cb + 1 == 3) ? 0 : cb + 1;
  }

  // epilogue: out = wbe*acc + wa*ba + wbe*bb
  const float* ba = eb + ea * 1024;
  const float* bb = eb + ebx * 1024;
#pragma unroll
  for (int m = 0; m < 4; ++m) {
#pragma unroll
    for (int r = 0; r < 4; ++r) {
      int g = m0 + wr * 64 + m * 16 + ((lane >> 4) << 2) + r;
      if (g < segN) {
        int p = seg0 + g;
        float wa = wav[m][r], we = wbe[m][r];
        int token = row_tok[p];
        float* op = out + (size_t)token * 1024;
#pragma unroll
        for (int n = 0; n < 8; ++n) {
          int col = n0 + wc * 128 + n * 16 + (lane & 15);
          op[col] = we * acc[m][n][r] + wa * ba[col] + we * bb[col];
        }
      }
    }
  }
#undef STAGEJ
#undef STAGE5
}

extern "C" void kernel_launch(void* const* d_in, const int* in_sizes, int n_in,
                              void* d_out, int out_size, void* d_ws, size_t ws_size,
                              hipStream_t stream) {
  const float* x  = (const float*)d_in[0];
  const float* gw = (const float*)d_in[1];
  const float* gb = (const float*)d_in[2];
  const float* ew = (const float*)d_in[3];
  const float* eb = (const float*)d_in[4];
  float* out = (float*)d_out;
  float* logits = out + (size_t)T_TOKENS * 1024;

  char* ws = (char*)d_ws;
  unsigned short* xw   = (unsigned short*)(ws);                 // 16 MB (single unscaled copy)
  unsigned short* w_bf = (unsigned short*)(ws + 16777216);      // 16 MB
  int*    tk_e     = (int*)(ws + 33554432);
  float*  tk_w     = (float*)(ws + 33619968);
  int*    row_tok  = (int*)(ws + 33685504);
  float2* row_wab  = (float2*)(ws + 33751040);
  int*    offsets  = (int*)(ws + 33816576);   // 29 ints
  int*    pairAB   = (int*)(ws + 33816704);   // 28 ints
  int*    n_tiles  = (int*)(ws + 33816832);   // [0]=nb, [1]=cpx
  int*    tiles    = (int*)(ws + 33816960);   // up to ~200 ints

  router_kernel<<<2048, 256, 0, stream>>>(x, gw, gb, logits, xw, tk_e, tk_w);
  sortconv_kernel<<<2049, 1024, 0, stream>>>(ew, w_bf, tk_e, tk_w, offsets, row_tok,
                                             row_wab, pairAB, tiles, n_tiles);
  gemm_kernel<<<256, 512, 0, stream>>>(xw, w_bf, row_tok, row_wab, offsets, pairAB,
                                       tiles, n_tiles, eb, out);
}